// Round 5
// baseline (187.102 us; speedup 1.0000x reference)
//
#include <hip/hip_runtime.h>

// Problem constants
#define DM    1024
#define NH    16
#define HD    64
#define SEQ   2048
#define BATCH 2
#define NQKV  3072          // 3*DM
#define MTOT  4096          // BATCH*SEQ

using half2v = __attribute__((ext_vector_type(2))) _Float16;
using half4  = __attribute__((ext_vector_type(4))) _Float16;
using half8  = __attribute__((ext_vector_type(8))) _Float16;
using f32x4  = __attribute__((ext_vector_type(4))) float;

typedef const __attribute__((address_space(1))) unsigned int* gp_t;
typedef __attribute__((address_space(3))) unsigned int* lp_t;

// async global->LDS, 16B per lane. LDS dest is wave-uniform base + lane*16
// (HW-pinned), so LDS swizzle is implemented by permuting the global SOURCE
// column per lane; readers apply the same XOR.
__device__ __forceinline__ void gl2lds16(const void* g, void* l) {
    __builtin_amdgcn_global_load_lds((gp_t)g, (lp_t)l, 16, 0, 0);
}

__device__ __forceinline__ f32x4 fzero4() {
    f32x4 v; v[0] = 0.f; v[1] = 0.f; v[2] = 0.f; v[3] = 0.f; return v;
}

// XOR-swizzled LDS indexing (units = halves, chunks = 16B = 8 halves).
__device__ __forceinline__ int sw8(int row, int col) {   // 64-half rows
    return (row << 6) | ((((col >> 3) ^ row) & 7) << 3) | (col & 7);
}

#define CSCALE 0.18033688011112042f   // (1/8) * log2(e) — folded into Q weights

// packed exp2 + f32->f16 convert (v_exp_f32 x2 + v_cvt_pkrtz_f16_f32)
__device__ __forceinline__ half2v expp2(float a, float b) {
    return __builtin_bit_cast(half2v, __builtin_amdgcn_cvt_pkrtz(
        __builtin_amdgcn_exp2f(a), __builtin_amdgcn_exp2f(b)));
}

// T4 counted-vmcnt acquire / release barriers (raw s_barrier — __syncthreads
// would drain vmcnt(0) and serialize the pipeline).  sched_barrier(0) pins
// code motion across the inline-asm waits (rule #18).
#define ACQ(N) do {                                             \
    asm volatile("s_waitcnt vmcnt(" #N ")" ::: "memory");       \
    __builtin_amdgcn_sched_barrier(0);                          \
    __builtin_amdgcn_s_barrier();                               \
    __builtin_amdgcn_sched_barrier(0);                          \
} while (0)
#define REL() do {                                              \
    __builtin_amdgcn_sched_barrier(0);                          \
    asm volatile("s_waitcnt lgkmcnt(0)" ::: "memory");          \
    __builtin_amdgcn_s_barrier();                               \
    __builtin_amdgcn_sched_barrier(0);                          \
} while (0)

// ------------------------------------------- fused fp32 -> fp16 (X, Wqkv, Wo)
// Also: scales the Q-rows of Wqkv by CSCALE (so QK^T scores arrive in
// exp2-ready units) and emits a matching scaled f32 copy of bqkv.
__global__ __launch_bounds__(256) void cvt_all(const float* __restrict__ X,
                                               const float* __restrict__ W1,
                                               const float* __restrict__ W2,
                                               const float* __restrict__ bqkv,
                                               float* __restrict__ bscaled,
                                               _Float16* __restrict__ out) {
    const int nX = MTOT * DM / 4, nW1 = NQKV * DM / 4, nW2 = DM * DM / 4;
    int i = blockIdx.x * 256 + threadIdx.x;
    if (i < NQKV) {
        const float b = bqkv[i];
        bscaled[i] = ((i % 192) < 64) ? b * CSCALE : b;
    }
    if (i >= nX + nW1 + nW2) return;
    float4 f;
    float sc = 1.0f;
    if (i < nX) {
        f = reinterpret_cast<const float4*>(X)[i];
    } else if (i < nX + nW1) {
        const int off = i - nX;
        f = reinterpret_cast<const float4*>(W1)[off];
        const int row = off >> 8;            // 256 float4 per 1024-wide row
        if ((row % 192) < 64) sc = CSCALE;   // Q-rows of Wqkv
    } else {
        f = reinterpret_cast<const float4*>(W2)[i - nX - nW1];
    }
    half4 h;
    h[0] = (_Float16)(f.x * sc); h[1] = (_Float16)(f.y * sc);
    h[2] = (_Float16)(f.z * sc); h[3] = (_Float16)(f.w * sc);
    reinterpret_cast<half4*>(out)[i] = h;
}

// ------------------------------------------------- NT GEMM, pipelined (R5)
// C[m][n] = sum_k A[m][k]*B[n][k] + bias[n].  128x128 tile, BK=64, 4 waves
// in 2x2, each wave 64x64 via 4x4 MFMA 16x16x32_f16 tiles. XOR-swizzled LDS.
// R5: double-buffered LDS (64 KB) + counted-vmcnt ACQ/REL pipeline — the
// per-tile __syncthreads drained vmcnt(0) every K-step (same pathology fixed
// in attn R2, -17%).  Depth-1 prefetch: A/B panels are L2-resident (X panel
// reused across N-blocks; Wqkv = 6 MB < 4 MB/XCD x hits), so ~200-400 cyc
// latency hides under the ~620-cyc MFMA phase.
template <bool OUT_F16>
__global__ __launch_bounds__(256) void gemm_nt(const _Float16* __restrict__ A,
                                               const _Float16* __restrict__ B,
                                               const float* __restrict__ bias,
                                               void* __restrict__ Cout,
                                               int M, int N, int K) {
    __shared__ _Float16 lA[2][128 * 64];
    __shared__ _Float16 lB[2][128 * 64];
    const int tid = threadIdx.x;
    const int m0 = blockIdx.y * 128, n0 = blockIdx.x * 128;
    const int wave = tid >> 6, lane = tid & 63, quad = lane >> 4, l15 = lane & 15;
    const int wm = (wave & 1) * 64, wn = (wave >> 1) * 64;

    f32x4 acc[4][4];
#pragma unroll
    for (int i = 0; i < 4; ++i)
#pragma unroll
        for (int j = 0; j < 4; ++j) acc[i][j] = fzero4();

    const int cperm = (((tid & 7) ^ (tid >> 3)) & 7) * 8;
    const _Float16* Ab = A + (long)(m0 + (tid >> 3)) * K + cperm;
    const _Float16* Bb = B + (long)(n0 + (tid >> 3)) * K + cperm;

    const int nkt = K >> 6;
    // prologue: stage tile 0 into buffer 0 (8 loads/thread)
#pragma unroll
    for (int j = 0; j < 4; ++j) {
        gl2lds16(Ab + (long)j * 32 * K, (char*)lA[0] + j * 4096 + tid * 16);
        gl2lds16(Bb + (long)j * 32 * K, (char*)lB[0] + j * 4096 + tid * 16);
    }

    for (int t = 0; t < nkt; ++t) {
        const int cur = t & 1;
        if (t + 1 < nkt) {
            const long kn = (long)(t + 1) * 64;
#pragma unroll
            for (int j = 0; j < 4; ++j) {
                gl2lds16(Ab + (long)j * 32 * K + kn, (char*)lA[cur ^ 1] + j * 4096 + tid * 16);
                gl2lds16(Bb + (long)j * 32 * K + kn, (char*)lB[cur ^ 1] + j * 4096 + tid * 16);
            }
            ACQ(8);      // tile t landed; tile t+1's 8 loads stay in flight
        } else {
            ACQ(0);      // last tile: drain
        }
#pragma unroll
        for (int ks = 0; ks < 2; ++ks) {
            half8 af[4], bfr[4];
#pragma unroll
            for (int tt = 0; tt < 4; ++tt) {
                af[tt]  = *(const half8*)(lA[cur] + sw8(wm + tt * 16 + l15, ks * 32 + quad * 8));
                bfr[tt] = *(const half8*)(lB[cur] + sw8(wn + tt * 16 + l15, ks * 32 + quad * 8));
            }
#pragma unroll
            for (int mt = 0; mt < 4; ++mt)
#pragma unroll
                for (int nt = 0; nt < 4; ++nt)
                    acc[mt][nt] = __builtin_amdgcn_mfma_f32_16x16x32_f16(
                        af[mt], bfr[nt], acc[mt][nt], 0, 0, 0);
        }
        if (t + 1 < nkt) REL();   // reads done; buffer free for next overwrite
    }

    float bs[4];
#pragma unroll
    for (int nt = 0; nt < 4; ++nt) bs[nt] = bias[n0 + wn + nt * 16 + l15];

#pragma unroll
    for (int mt = 0; mt < 4; ++mt) {
#pragma unroll
        for (int r = 0; r < 4; ++r) {
            const int m = m0 + wm + mt * 16 + quad * 4 + r;
#pragma unroll
            for (int nt = 0; nt < 4; ++nt) {
                const int n = n0 + wn + nt * 16 + l15;
                const float v = acc[mt][nt][r] + bs[nt];
                if constexpr (OUT_F16)
                    ((_Float16*)Cout)[(long)m * N + n] = (_Float16)v;
                else
                    ((float*)Cout)[(long)m * N + n] = v;
            }
        }
    }
}

// -------------------- NT GEMM, 64x128 tile, pipelined (R5, same transform)
template <bool OUT_F16>
__global__ __launch_bounds__(256) void gemm_nt_64(const _Float16* __restrict__ A,
                                                  const _Float16* __restrict__ B,
                                                  const float* __restrict__ bias,
                                                  void* __restrict__ Cout,
                                                  int M, int N, int K) {
    __shared__ _Float16 lA[2][64 * 64];
    __shared__ _Float16 lB[2][128 * 64];
    const int tid = threadIdx.x;
    const int m0 = blockIdx.y * 64, n0 = blockIdx.x * 128;
    const int wave = tid >> 6, lane = tid & 63, quad = lane >> 4, l15 = lane & 15;
    const int wm = (wave & 1) * 32, wn = (wave >> 1) * 64;

    f32x4 acc[2][4];
#pragma unroll
    for (int i = 0; i < 2; ++i)
#pragma unroll
        for (int j = 0; j < 4; ++j) acc[i][j] = fzero4();

    const int cperm = (((tid & 7) ^ (tid >> 3)) & 7) * 8;
    const _Float16* Ab = A + (long)(m0 + (tid >> 3)) * K + cperm;
    const _Float16* Bb = B + (long)(n0 + (tid >> 3)) * K + cperm;

    const int nkt = K >> 6;
    // prologue: stage tile 0 (6 loads/thread)
#pragma unroll
    for (int j = 0; j < 2; ++j)
        gl2lds16(Ab + (long)j * 32 * K, (char*)lA[0] + j * 4096 + tid * 16);
#pragma unroll
    for (int j = 0; j < 4; ++j)
        gl2lds16(Bb + (long)j * 32 * K, (char*)lB[0] + j * 4096 + tid * 16);

    for (int t = 0; t < nkt; ++t) {
        const int cur = t & 1;
        if (t + 1 < nkt) {
            const long kn = (long)(t + 1) * 64;
#pragma unroll
            for (int j = 0; j < 2; ++j)
                gl2lds16(Ab + (long)j * 32 * K + kn, (char*)lA[cur ^ 1] + j * 4096 + tid * 16);
#pragma unroll
            for (int j = 0; j < 4; ++j)
                gl2lds16(Bb + (long)j * 32 * K + kn, (char*)lB[cur ^ 1] + j * 4096 + tid * 16);
            ACQ(6);
        } else {
            ACQ(0);
        }
#pragma unroll
        for (int ks = 0; ks < 2; ++ks) {
            half8 af[2], bfr[4];
#pragma unroll
            for (int tt = 0; tt < 2; ++tt)
                af[tt] = *(const half8*)(lA[cur] + sw8(wm + tt * 16 + l15, ks * 32 + quad * 8));
#pragma unroll
            for (int tt = 0; tt < 4; ++tt)
                bfr[tt] = *(const half8*)(lB[cur] + sw8(wn + tt * 16 + l15, ks * 32 + quad * 8));
#pragma unroll
            for (int mt = 0; mt < 2; ++mt)
#pragma unroll
                for (int nt = 0; nt < 4; ++nt)
                    acc[mt][nt] = __builtin_amdgcn_mfma_f32_16x16x32_f16(
                        af[mt], bfr[nt], acc[mt][nt], 0, 0, 0);
        }
        if (t + 1 < nkt) REL();
    }

    float bs[4];
#pragma unroll
    for (int nt = 0; nt < 4; ++nt) bs[nt] = bias[n0 + wn + nt * 16 + l15];

#pragma unroll
    for (int mt = 0; mt < 2; ++mt) {
#pragma unroll
        for (int r = 0; r < 4; ++r) {
            const int m = m0 + wm + mt * 16 + quad * 4 + r;
#pragma unroll
            for (int nt = 0; nt < 4; ++nt) {
                const int n = n0 + wn + nt * 16 + l15;
                const float v = acc[mt][nt][r] + bs[nt];
                if constexpr (OUT_F16)
                    ((_Float16*)Cout)[(long)m * N + n] = (_Float16)v;
                else
                    ((float*)Cout)[(long)m * N + n] = v;
            }
        }
    }
}

// ------------- V repack: qkv[B,S,H*192] -> Vt[B,H,64,S] with key permutation
// Within each 32-key group, key (16*hi + 4*q + r) is stored at position
// (8*q + 4*hi + r).  Then the attention PV B-fragment (lane quad needs keys
// {q*4+r} and {16+q*4+r}) is 8 CONTIGUOUS halves at position q*8 — a single
// aligned 16B LDS read (the conflict-free pattern), matching the P A-frag
// packing exactly.
__global__ __launch_bounds__(256) void repack_v(const _Float16* __restrict__ qkvh,
                                                _Float16* __restrict__ vt) {
    const int b = blockIdx.z, h = blockIdx.y, s0 = blockIdx.x * 32;
    const int d = threadIdx.x & 63, si = threadIdx.x >> 6;   // si = quad q
    const _Float16* src = qkvh + (long)(b * SEQ + s0) * NQKV + h * 192 + 128 + d;
    half8 v;
#pragma unroll
    for (int hi = 0; hi < 2; ++hi)
#pragma unroll
        for (int r = 0; r < 4; ++r)
            v[hi * 4 + r] = src[(long)(hi * 16 + si * 4 + r) * NQKV];
    *(half8*)(vt + (long)((b * NH + h) * HD + d) * SEQ + s0 + si * 8) = v;
}

// ----------------------------------------------------- flash attention fwd
// Per block: (b, h, 128 q-rows), 512 threads = 8 waves.  Waves are paired:
// wave w and w+4 both own q rows [(w&3)*32, +32) — group g=wave>>2 takes the
// even (g=0) / odd (g=1) 64-key tiles.  Each block-iter stages 128 keys
// (4 x 8KB tiles, ONE gl2lds16 each at 512 thr), double-buffered (64 KB).
// At the end wave pairs merge partial O/lsum through LDS (exp2-prescaled
// scores -> no max bookkeeping, partials just add).
//
// R5 change: T5 s_setprio(1) around the QK and PV MFMA clusters.  R4's wall
// (1525 cyc per 128qx64k unit) ~ MFMA(700) + LDS(~850) SUMMED, not
// overlapped — all waves burst ds_reads together after ACQ, then all MFMA
// together.  setprio lets MFMA-phase waves preempt load-phase waves
// (+21-39% on counted-vmcnt GEMM schedules, m218b/m224).
__global__ __launch_bounds__(512) void attn_flash(const _Float16* __restrict__ qkv,
                                                  const _Float16* __restrict__ vt,
                                                  _Float16* __restrict__ aout) {
    __shared__ _Float16 lbuf[8][64 * 64];   // 64 KB: 2 sets x {K0,K1,V0,V1}

    // XCD-aware decode (dispatch round-robins linear block id over 8 XCDs):
    // all 16 q-tiles of one (b,h) land on one XCD -> K/V re-reads hit its L2.
    const int L = blockIdx.x + 16 * blockIdx.y + 256 * blockIdx.z;  // 0..511
    const int c = L & 7, j = L >> 3;        // XCD c, 64 blocks per XCD
    const int pair = c * 4 + (j >> 4);      // 32 (b,h) pairs, 4 per XCD
    const int b = pair >> 4, h = pair & 15;
    const int q0 = (j & 15) * 128;

    const int tid = threadIdx.x;
    const int wave = tid >> 6, lane = tid & 63, quad = lane >> 4, l15 = lane & 15;
    const int wq = wave & 3;                // q-subtile (shared by wave pair)
    const int g  = wave >> 2;               // key-half group: 0=even, 1=odd tile
    const int cperm8 = (((tid & 7) ^ (tid >> 3)) & 7) * 8;
    const int srow = tid >> 3;              // 0..63: row staged by this thread

    // stage Q tile [128][64] (swizzled) into lbuf[0..1] (16 KB)
    const _Float16* qsrc = qkv + (long)(b * SEQ + q0 + srow) * NQKV + h * 192 + cperm8;
    gl2lds16(qsrc,                   (char*)lbuf + tid * 16);
    gl2lds16(qsrc + (long)64 * NQKV, (char*)lbuf + 8192 + tid * 16);
    __syncthreads();   // Q landed (drains vmcnt — prologue only)

    half8 qf[2][2];
#pragma unroll
    for (int qt = 0; qt < 2; ++qt)
#pragma unroll
        for (int ks = 0; ks < 2; ++ks)
            qf[qt][ks] = *(const half8*)((const _Float16*)lbuf +
                             sw8(wq * 32 + qt * 16 + l15, ks * 32 + quad * 8));
    __syncthreads();   // all Q reads done; K buffers free

    f32x4 O[2][4];
#pragma unroll
    for (int qt = 0; qt < 2; ++qt)
#pragma unroll
        for (int dt = 0; dt < 4; ++dt) O[qt][dt] = fzero4();
    f32x4 lsum[2] = {fzero4(), fzero4()};

    half8 ones;
#pragma unroll
    for (int i = 0; i < 8; ++i) ones[i] = (_Float16)1.0f;

    const _Float16* ksrc = qkv + (long)(b * SEQ + srow) * NQKV + h * 192 + 64 + cperm8;
    const _Float16* vsrc = vt + (long)((b * NH + h) * HD + srow) * SEQ + cperm8;

    // prologue: issue sets for iters 0 and 1 (kb = 0, 128).  Each 8 KB tile
    // is ONE gl2lds16 at 512 threads.  Outstanding per wave = 8.
#pragma unroll
    for (int s = 0; s < 2; ++s) {
        const long kb = (long)s * 128;
        gl2lds16(ksrc + kb * NQKV,         (char*)lbuf[s * 4 + 0] + tid * 16);
        gl2lds16(ksrc + (kb + 64) * NQKV,  (char*)lbuf[s * 4 + 1] + tid * 16);
        gl2lds16(vsrc + kb,                (char*)lbuf[s * 4 + 2] + tid * 16);
        gl2lds16(vsrc + kb + 64,           (char*)lbuf[s * 4 + 3] + tid * 16);
    }

    // per-64-key-tile compute for this wave's 32 q (2 MFMA per LDS read)
    auto computeg = [&](const _Float16* lK, const _Float16* lV) {
#pragma unroll
        for (int t = 0; t < 2; ++t) {
            f32x4 s[2][2];
            s[0][0] = fzero4(); s[0][1] = fzero4();
            s[1][0] = fzero4(); s[1][1] = fzero4();
            __builtin_amdgcn_s_setprio(1);
#pragma unroll
            for (int tt = 0; tt < 2; ++tt)
#pragma unroll
                for (int ks = 0; ks < 2; ++ks) {
                    half8 kf = *(const half8*)(lK + sw8((2 * t + tt) * 16 + l15, ks * 32 + quad * 8));
                    s[0][tt] = __builtin_amdgcn_mfma_f32_16x16x32_f16(kf, qf[0][ks], s[0][tt], 0, 0, 0);
                    s[1][tt] = __builtin_amdgcn_mfma_f32_16x16x32_f16(kf, qf[1][ks], s[1][tt], 0, 0, 0);
                }
            __builtin_amdgcn_s_setprio(0);
            half8 pf[2];
#pragma unroll
            for (int qt = 0; qt < 2; ++qt) {
                half2v p01 = expp2(s[qt][0][0], s[qt][0][1]);
                half2v p23 = expp2(s[qt][0][2], s[qt][0][3]);
                half2v p45 = expp2(s[qt][1][0], s[qt][1][1]);
                half2v p67 = expp2(s[qt][1][2], s[qt][1][3]);
                half4 lo = __builtin_shufflevector(p01, p23, 0, 1, 2, 3);
                half4 hi = __builtin_shufflevector(p45, p67, 0, 1, 2, 3);
                pf[qt] = __builtin_shufflevector(lo, hi, 0, 1, 2, 3, 4, 5, 6, 7);
            }
            __builtin_amdgcn_s_setprio(1);
            lsum[0] = __builtin_amdgcn_mfma_f32_16x16x32_f16(pf[0], ones, lsum[0], 0, 0, 0);
            lsum[1] = __builtin_amdgcn_mfma_f32_16x16x32_f16(pf[1], ones, lsum[1], 0, 0, 0);
#pragma unroll
            for (int dt = 0; dt < 4; ++dt) {
                // single aligned half8: V^T key-permuted so lane quad's 8 keys
                // are contiguous at position t*32 + quad*8
                half8 vf = *(const half8*)(lV + sw8(dt * 16 + l15, t * 32 + quad * 8));
                O[0][dt] = __builtin_amdgcn_mfma_f32_16x16x32_f16(pf[0], vf, O[0][dt], 0, 0, 0);
                O[1][dt] = __builtin_amdgcn_mfma_f32_16x16x32_f16(pf[1], vf, O[1][dt], 0, 0, 0);
            }
            __builtin_amdgcn_s_setprio(0);
        }
    };

    // iter 0: compute set0 (set1's 4 loads stay in flight)
    ACQ(4);
    computeg(lbuf[g], lbuf[2 + g]);
    REL();
    // iters 1..14: issue iter it+1's set (into the buffer freed by it-1's
    // REL), wait iter it's set (vmcnt(4): newer 4 in flight), compute.
    for (int it = 1; it <= 14; ++it) {
        const int ns = ((it + 1) & 1) * 4;
        const long kb = (long)(it + 1) * 128;
        gl2lds16(ksrc + kb * NQKV,        (char*)lbuf[ns + 0] + tid * 16);
        gl2lds16(ksrc + (kb + 64) * NQKV, (char*)lbuf[ns + 1] + tid * 16);
        gl2lds16(vsrc + kb,               (char*)lbuf[ns + 2] + tid * 16);
        gl2lds16(vsrc + kb + 64,          (char*)lbuf[ns + 3] + tid * 16);
        const int cs = (it & 1) * 4;
        ACQ(4);
        computeg(lbuf[cs + g], lbuf[cs + 2 + g]);
        REL();
    }
    // iter 15: last set, nothing else in flight
    ACQ(0);
    computeg(lbuf[4 + g], lbuf[6 + g]);
    __syncthreads();   // drains ds reads; all 64 KB LDS now free for combine

    // wave-pair combine: waves 4-7 hand their partial O/lsum to waves 0-3.
    // stride 41 f32 per lane -> 41 mod 32 coprime -> conflict-free one-shot.
    float* red = (float*)lbuf;
    const int slot = (wq * 64 + lane) * 41;
    if (wave >= 4) {
        float* p = red + slot;
#pragma unroll
        for (int qt = 0; qt < 2; ++qt)
#pragma unroll
            for (int dt = 0; dt < 4; ++dt)
#pragma unroll
                for (int r = 0; r < 4; ++r) p[qt * 16 + dt * 4 + r] = O[qt][dt][r];
#pragma unroll
        for (int qt = 0; qt < 2; ++qt)
#pragma unroll
            for (int r = 0; r < 4; ++r) p[32 + qt * 4 + r] = lsum[qt][r];
    }
    __syncthreads();
    if (wave < 4) {
        const float* p = red + slot;
#pragma unroll
        for (int qt = 0; qt < 2; ++qt)
#pragma unroll
            for (int dt = 0; dt < 4; ++dt)
#pragma unroll
                for (int r = 0; r < 4; ++r) O[qt][dt][r] += p[qt * 16 + dt * 4 + r];
#pragma unroll
        for (int qt = 0; qt < 2; ++qt)
#pragma unroll
            for (int r = 0; r < 4; ++r) lsum[qt][r] += p[32 + qt * 4 + r];

        // epilogue: O / l (lsum in C-layout rows), store f16
#pragma unroll
        for (int qt = 0; qt < 2; ++qt) {
#pragma unroll
            for (int r = 0; r < 4; ++r) {
                const float lr = 1.0f / lsum[qt][r];
                const int row = b * SEQ + q0 + wq * 32 + qt * 16 + quad * 4 + r;
#pragma unroll
                for (int dt = 0; dt < 4; ++dt)
                    aout[(long)row * DM + h * HD + dt * 16 + l15] =
                        (_Float16)(O[qt][dt][r] * lr);
            }
        }
    }
}

// --------------------------------------------------------------------- launch
extern "C" void kernel_launch(void* const* d_in, const int* in_sizes, int n_in,
                              void* d_out, int out_size, void* d_ws, size_t ws_size,
                              hipStream_t stream) {
    const float* X    = (const float*)d_in[0];
    const float* Wqkv = (const float*)d_in[1];
    const float* bqkv = (const float*)d_in[2];
    const float* Wo   = (const float*)d_in[3];
    const float* bo   = (const float*)d_in[4];

    // workspace layout (56 MB total); Xh/Wqh/Woh contiguous for fused convert.
    // bscaled lives at the head of the atth region: consumed by the QKV GEMM
    // before attn overwrites atth.
    char* ws = (char*)d_ws;
    _Float16* Xh   = (_Float16*)(ws);                        //  8 MB  [MTOT, DM]
    _Float16* Wqh  = (_Float16*)(ws + (size_t)8  * 1048576); //  6 MB  [NQKV, DM]
    _Float16* Woh  = (_Float16*)(ws + (size_t)14 * 1048576); //  2 MB  [DM, DM]
    _Float16* qkvh = (_Float16*)(ws + (size_t)16 * 1048576); // 24 MB  [MTOT, NQKV]
    _Float16* vth  = (_Float16*)(ws + (size_t)40 * 1048576); //  8 MB  [B, H, HD, SEQ]
    _Float16* atth = (_Float16*)(ws + (size_t)48 * 1048576); //  8 MB  [MTOT, DM]
    float* bscaled = (float*)(ws + (size_t)48 * 1048576);    // 12 KB (dead after QKV GEMM)

    const int ncvt = (MTOT * DM + NQKV * DM + DM * DM) / 4;
    cvt_all<<<(ncvt + 255) / 256, 256, 0, stream>>>(X, Wqkv, Wo, bqkv, bscaled, Xh);

    gemm_nt<true><<<dim3(NQKV / 128, MTOT / 128), 256, 0, stream>>>(
        Xh, Wqh, bscaled, qkvh, MTOT, NQKV, DM);

    repack_v<<<dim3(SEQ / 32, NH, BATCH), 256, 0, stream>>>(qkvh, vth);

    attn_flash<<<dim3(SEQ / 128, NH, BATCH), 512, 0, stream>>>(qkvh, vth, atth);

    gemm_nt_64<false><<<dim3(DM / 128, MTOT / 64), 256, 0, stream>>>(
        atth, Woh, bo, d_out, MTOT, DM, DM);
}

// Round 7
// 183.499 us; speedup vs baseline: 1.0196x; 1.0196x over previous
//
#include <hip/hip_runtime.h>

// Problem constants
#define DM    1024
#define NH    16
#define HD    64
#define SEQ   2048
#define BATCH 2
#define NQKV  3072          // 3*DM
#define MTOT  4096          // BATCH*SEQ

using half2v = __attribute__((ext_vector_type(2))) _Float16;
using half4  = __attribute__((ext_vector_type(4))) _Float16;
using half8  = __attribute__((ext_vector_type(8))) _Float16;
using f32x4  = __attribute__((ext_vector_type(4))) float;

typedef const __attribute__((address_space(1))) unsigned int* gp_t;
typedef __attribute__((address_space(3))) unsigned int* lp_t;

// async global->LDS, 16B per lane. LDS dest is wave-uniform base + lane*16
// (HW-pinned), so LDS swizzle is implemented by permuting the global SOURCE
// column per lane; readers apply the same XOR.
__device__ __forceinline__ void gl2lds16(const void* g, void* l) {
    __builtin_amdgcn_global_load_lds((gp_t)g, (lp_t)l, 16, 0, 0);
}

__device__ __forceinline__ f32x4 fzero4() {
    f32x4 v; v[0] = 0.f; v[1] = 0.f; v[2] = 0.f; v[3] = 0.f; return v;
}

// XOR-swizzled LDS indexing (units = halves, chunks = 16B = 8 halves).
__device__ __forceinline__ int sw8(int row, int col) {   // 64-half rows
    return (row << 6) | ((((col >> 3) ^ row) & 7) << 3) | (col & 7);
}

#define CSCALE 0.18033688011112042f   // (1/8) * log2(e) — folded into Q weights

// packed exp2 + f32->f16 convert (v_exp_f32 x2 + v_cvt_pkrtz_f16_f32)
__device__ __forceinline__ half2v expp2(float a, float b) {
    return __builtin_bit_cast(half2v, __builtin_amdgcn_cvt_pkrtz(
        __builtin_amdgcn_exp2f(a), __builtin_amdgcn_exp2f(b)));
}

// T4 counted-vmcnt acquire / release barriers (raw s_barrier — __syncthreads
// would drain vmcnt(0) and serialize the pipeline).  sched_barrier(0) pins
// code motion across the inline-asm waits (rule #18).  USED IN ATTN ONLY:
// R5 showed the same transform on the 4-wave GEMM costs occupancy (5->2
// blocks/CU at 64 KB LDS) and regresses 35->50.7 us — m97-structure GEMMs
// keep the plain __syncthreads loop (guide m99/m100/m131-m140 nulls).
#define ACQ(N) do {                                             \
    asm volatile("s_waitcnt vmcnt(" #N ")" ::: "memory");       \
    __builtin_amdgcn_sched_barrier(0);                          \
    __builtin_amdgcn_s_barrier();                               \
    __builtin_amdgcn_sched_barrier(0);                          \
} while (0)
#define REL() do {                                              \
    __builtin_amdgcn_sched_barrier(0);                          \
    asm volatile("s_waitcnt lgkmcnt(0)" ::: "memory");          \
    __builtin_amdgcn_s_barrier();                               \
    __builtin_amdgcn_sched_barrier(0);                          \
} while (0)

// ------------------------------------------- fused fp32 -> fp16 (X, Wqkv, Wo)
// Also: scales the Q-rows of Wqkv by CSCALE (so QK^T scores arrive in
// exp2-ready units) and emits a matching scaled f32 copy of bqkv.
__global__ __launch_bounds__(256) void cvt_all(const float* __restrict__ X,
                                               const float* __restrict__ W1,
                                               const float* __restrict__ W2,
                                               const float* __restrict__ bqkv,
                                               float* __restrict__ bscaled,
                                               _Float16* __restrict__ out) {
    const int nX = MTOT * DM / 4, nW1 = NQKV * DM / 4, nW2 = DM * DM / 4;
    int i = blockIdx.x * 256 + threadIdx.x;
    if (i < NQKV) {
        const float b = bqkv[i];
        bscaled[i] = ((i % 192) < 64) ? b * CSCALE : b;
    }
    if (i >= nX + nW1 + nW2) return;
    float4 f;
    float sc = 1.0f;
    if (i < nX) {
        f = reinterpret_cast<const float4*>(X)[i];
    } else if (i < nX + nW1) {
        const int off = i - nX;
        f = reinterpret_cast<const float4*>(W1)[off];
        const int row = off >> 8;            // 256 float4 per 1024-wide row
        if ((row % 192) < 64) sc = CSCALE;   // Q-rows of Wqkv
    } else {
        f = reinterpret_cast<const float4*>(W2)[i - nX - nW1];
    }
    half4 h;
    h[0] = (_Float16)(f.x * sc); h[1] = (_Float16)(f.y * sc);
    h[2] = (_Float16)(f.z * sc); h[3] = (_Float16)(f.w * sc);
    reinterpret_cast<half4*>(out)[i] = h;
}

// ------------------------------------------------- NT GEMM (m97 structure)
// C[m][n] = sum_k A[m][k]*B[n][k] + bias[n].  128x128 tile, BK=64, 4 waves
// in 2x2, each wave 64x64 via 4x4 MFMA 16x16x32_f16 tiles. XOR-swizzled LDS.
// R6: reverted to the R4 __syncthreads version — 32 KB LDS keeps 5
// blocks/CU; the R5 counted-vmcnt dbuf (64 KB) dropped occupancy to
// ~1.5 blocks/CU and regressed 35 -> 50.7 us.
template <bool OUT_F16>
__global__ __launch_bounds__(256) void gemm_nt(const _Float16* __restrict__ A,
                                               const _Float16* __restrict__ B,
                                               const float* __restrict__ bias,
                                               void* __restrict__ Cout,
                                               int M, int N, int K) {
    __shared__ _Float16 lA[128 * 64];
    __shared__ _Float16 lB[128 * 64];
    const int tid = threadIdx.x;
    const int m0 = blockIdx.y * 128, n0 = blockIdx.x * 128;
    const int wave = tid >> 6, lane = tid & 63, quad = lane >> 4, l15 = lane & 15;
    const int wm = (wave & 1) * 64, wn = (wave >> 1) * 64;

    f32x4 acc[4][4];
#pragma unroll
    for (int i = 0; i < 4; ++i)
#pragma unroll
        for (int j = 0; j < 4; ++j) acc[i][j] = fzero4();

    const int cperm = (((tid & 7) ^ (tid >> 3)) & 7) * 8;
    const _Float16* Ab = A + (long)(m0 + (tid >> 3)) * K + cperm;
    const _Float16* Bb = B + (long)(n0 + (tid >> 3)) * K + cperm;
    char* lAp = (char*)lA + tid * 16;
    char* lBp = (char*)lB + tid * 16;

    for (int kt = 0; kt < K; kt += 64) {
        __syncthreads();
#pragma unroll
        for (int j = 0; j < 4; ++j) {
            gl2lds16(Ab + (long)j * 32 * K + kt, lAp + j * 4096);
            gl2lds16(Bb + (long)j * 32 * K + kt, lBp + j * 4096);
        }
        __syncthreads();
#pragma unroll
        for (int ks = 0; ks < 2; ++ks) {
            half8 af[4], bfr[4];
#pragma unroll
            for (int t = 0; t < 4; ++t) {
                af[t]  = *(const half8*)(lA + sw8(wm + t * 16 + l15, ks * 32 + quad * 8));
                bfr[t] = *(const half8*)(lB + sw8(wn + t * 16 + l15, ks * 32 + quad * 8));
            }
#pragma unroll
            for (int mt = 0; mt < 4; ++mt)
#pragma unroll
                for (int nt = 0; nt < 4; ++nt)
                    acc[mt][nt] = __builtin_amdgcn_mfma_f32_16x16x32_f16(
                        af[mt], bfr[nt], acc[mt][nt], 0, 0, 0);
        }
    }

    float bs[4];
#pragma unroll
    for (int nt = 0; nt < 4; ++nt) bs[nt] = bias[n0 + wn + nt * 16 + l15];

#pragma unroll
    for (int mt = 0; mt < 4; ++mt) {
#pragma unroll
        for (int r = 0; r < 4; ++r) {
            const int m = m0 + wm + mt * 16 + quad * 4 + r;
#pragma unroll
            for (int nt = 0; nt < 4; ++nt) {
                const int n = n0 + wn + nt * 16 + l15;
                const float v = acc[mt][nt][r] + bs[nt];
                if constexpr (OUT_F16)
                    ((_Float16*)Cout)[(long)m * N + n] = (_Float16)v;
                else
                    ((float*)Cout)[(long)m * N + n] = v;
            }
        }
    }
}

// -------------------------------- NT GEMM, 64x128 tile (more blocks for small N)
// R6: reverted to the R4 __syncthreads version (same rationale as gemm_nt).
template <bool OUT_F16>
__global__ __launch_bounds__(256) void gemm_nt_64(const _Float16* __restrict__ A,
                                                  const _Float16* __restrict__ B,
                                                  const float* __restrict__ bias,
                                                  void* __restrict__ Cout,
                                                  int M, int N, int K) {
    __shared__ _Float16 lA[64 * 64];
    __shared__ _Float16 lB[128 * 64];
    const int tid = threadIdx.x;
    const int m0 = blockIdx.y * 64, n0 = blockIdx.x * 128;
    const int wave = tid >> 6, lane = tid & 63, quad = lane >> 4, l15 = lane & 15;
    const int wm = (wave & 1) * 32, wn = (wave >> 1) * 64;

    f32x4 acc[2][4];
#pragma unroll
    for (int i = 0; i < 2; ++i)
#pragma unroll
        for (int j = 0; j < 4; ++j) acc[i][j] = fzero4();

    const int cperm = (((tid & 7) ^ (tid >> 3)) & 7) * 8;
    const _Float16* Ab = A + (long)(m0 + (tid >> 3)) * K + cperm;
    const _Float16* Bb = B + (long)(n0 + (tid >> 3)) * K + cperm;
    char* lAp = (char*)lA + tid * 16;
    char* lBp = (char*)lB + tid * 16;

    for (int kt = 0; kt < K; kt += 64) {
        __syncthreads();
#pragma unroll
        for (int j = 0; j < 2; ++j)
            gl2lds16(Ab + (long)j * 32 * K + kt, lAp + j * 4096);
#pragma unroll
        for (int j = 0; j < 4; ++j)
            gl2lds16(Bb + (long)j * 32 * K + kt, lBp + j * 4096);
        __syncthreads();
#pragma unroll
        for (int ks = 0; ks < 2; ++ks) {
            half8 af[2], bfr[4];
#pragma unroll
            for (int t = 0; t < 2; ++t)
                af[t] = *(const half8*)(lA + sw8(wm + t * 16 + l15, ks * 32 + quad * 8));
#pragma unroll
            for (int t = 0; t < 4; ++t)
                bfr[t] = *(const half8*)(lB + sw8(wn + t * 16 + l15, ks * 32 + quad * 8));
#pragma unroll
            for (int mt = 0; mt < 2; ++mt)
#pragma unroll
                for (int nt = 0; nt < 4; ++nt)
                    acc[mt][nt] = __builtin_amdgcn_mfma_f32_16x16x32_f16(
                        af[mt], bfr[nt], acc[mt][nt], 0, 0, 0);
        }
    }

    float bs[4];
#pragma unroll
    for (int nt = 0; nt < 4; ++nt) bs[nt] = bias[n0 + wn + nt * 16 + l15];

#pragma unroll
    for (int mt = 0; mt < 2; ++mt) {
#pragma unroll
        for (int r = 0; r < 4; ++r) {
            const int m = m0 + wm + mt * 16 + quad * 4 + r;
#pragma unroll
            for (int nt = 0; nt < 4; ++nt) {
                const int n = n0 + wn + nt * 16 + l15;
                const float v = acc[mt][nt][r] + bs[nt];
                if constexpr (OUT_F16)
                    ((_Float16*)Cout)[(long)m * N + n] = (_Float16)v;
                else
                    ((float*)Cout)[(long)m * N + n] = v;
            }
        }
    }
}

// ------------- V repack: qkv[B,S,H*192] -> Vt[B,H,64,S] with key permutation
// Within each 32-key group, key (16*hi + 4*q + r) is stored at position
// (8*q + 4*hi + r).  Then the attention PV B-fragment (lane quad needs keys
// {q*4+r} and {16+q*4+r}) is 8 CONTIGUOUS halves at position q*8 — a single
// aligned 16B LDS read (the conflict-free pattern), matching the P A-frag
// packing exactly.
__global__ __launch_bounds__(256) void repack_v(const _Float16* __restrict__ qkvh,
                                                _Float16* __restrict__ vt) {
    const int b = blockIdx.z, h = blockIdx.y, s0 = blockIdx.x * 32;
    const int d = threadIdx.x & 63, si = threadIdx.x >> 6;   // si = quad q
    const _Float16* src = qkvh + (long)(b * SEQ + s0) * NQKV + h * 192 + 128 + d;
    half8 v;
#pragma unroll
    for (int hi = 0; hi < 2; ++hi)
#pragma unroll
        for (int r = 0; r < 4; ++r)
            v[hi * 4 + r] = src[(long)(hi * 16 + si * 4 + r) * NQKV];
    *(half8*)(vt + (long)((b * NH + h) * HD + d) * SEQ + s0 + si * 8) = v;
}

// ----------------------------------------------------- flash attention fwd
// Per block: (b, h, 128 q-rows), 512 threads = 8 waves.  Waves are paired:
// wave w and w+4 both own q rows [(w&3)*32, +32) — group g=wave>>2 takes the
// even (g=0) / odd (g=1) 64-key tiles.  Each block-iter stages 128 keys
// (4 x 8KB tiles, ONE gl2lds16 each at 512 thr), double-buffered (64 KB).
// At the end wave pairs merge partial O/lsum through LDS (exp2-prescaled
// scores -> no max bookkeeping, partials just add).
//
// R5's T5 s_setprio around the MFMA clusters kept (inferred -8 us: 40.7 ->
// ~32.5).  The counted-vmcnt pipeline (R2) + 32q/wave reuse at 4 waves/SIMD
// (R4) + setprio (R5) is the full attn technique stack.
__global__ __launch_bounds__(512) void attn_flash(const _Float16* __restrict__ qkv,
                                                  const _Float16* __restrict__ vt,
                                                  _Float16* __restrict__ aout) {
    __shared__ _Float16 lbuf[8][64 * 64];   // 64 KB: 2 sets x {K0,K1,V0,V1}

    // XCD-aware decode (dispatch round-robins linear block id over 8 XCDs):
    // all 16 q-tiles of one (b,h) land on one XCD -> K/V re-reads hit its L2.
    const int L = blockIdx.x + 16 * blockIdx.y + 256 * blockIdx.z;  // 0..511
    const int c = L & 7, j = L >> 3;        // XCD c, 64 blocks per XCD
    const int pair = c * 4 + (j >> 4);      // 32 (b,h) pairs, 4 per XCD
    const int b = pair >> 4, h = pair & 15;
    const int q0 = (j & 15) * 128;

    const int tid = threadIdx.x;
    const int wave = tid >> 6, lane = tid & 63, quad = lane >> 4, l15 = lane & 15;
    const int wq = wave & 3;                // q-subtile (shared by wave pair)
    const int g  = wave >> 2;               // key-half group: 0=even, 1=odd tile
    const int cperm8 = (((tid & 7) ^ (tid >> 3)) & 7) * 8;
    const int srow = tid >> 3;              // 0..63: row staged by this thread

    // stage Q tile [128][64] (swizzled) into lbuf[0..1] (16 KB)
    const _Float16* qsrc = qkv + (long)(b * SEQ + q0 + srow) * NQKV + h * 192 + cperm8;
    gl2lds16(qsrc,                   (char*)lbuf + tid * 16);
    gl2lds16(qsrc + (long)64 * NQKV, (char*)lbuf + 8192 + tid * 16);
    __syncthreads();   // Q landed (drains vmcnt — prologue only)

    half8 qf[2][2];
#pragma unroll
    for (int qt = 0; qt < 2; ++qt)
#pragma unroll
        for (int ks = 0; ks < 2; ++ks)
            qf[qt][ks] = *(const half8*)((const _Float16*)lbuf +
                             sw8(wq * 32 + qt * 16 + l15, ks * 32 + quad * 8));
    __syncthreads();   // all Q reads done; K buffers free

    f32x4 O[2][4];
#pragma unroll
    for (int qt = 0; qt < 2; ++qt)
#pragma unroll
        for (int dt = 0; dt < 4; ++dt) O[qt][dt] = fzero4();
    f32x4 lsum[2] = {fzero4(), fzero4()};

    half8 ones;
#pragma unroll
    for (int i = 0; i < 8; ++i) ones[i] = (_Float16)1.0f;

    const _Float16* ksrc = qkv + (long)(b * SEQ + srow) * NQKV + h * 192 + 64 + cperm8;
    const _Float16* vsrc = vt + (long)((b * NH + h) * HD + srow) * SEQ + cperm8;

    // prologue: issue sets for iters 0 and 1 (kb = 0, 128).  Each 8 KB tile
    // is ONE gl2lds16 at 512 threads.  Outstanding per wave = 8.
#pragma unroll
    for (int s = 0; s < 2; ++s) {
        const long kb = (long)s * 128;
        gl2lds16(ksrc + kb * NQKV,         (char*)lbuf[s * 4 + 0] + tid * 16);
        gl2lds16(ksrc + (kb + 64) * NQKV,  (char*)lbuf[s * 4 + 1] + tid * 16);
        gl2lds16(vsrc + kb,                (char*)lbuf[s * 4 + 2] + tid * 16);
        gl2lds16(vsrc + kb + 64,           (char*)lbuf[s * 4 + 3] + tid * 16);
    }

    // per-64-key-tile compute for this wave's 32 q (2 MFMA per LDS read)
    auto computeg = [&](const _Float16* lK, const _Float16* lV) {
#pragma unroll
        for (int t = 0; t < 2; ++t) {
            f32x4 s[2][2];
            s[0][0] = fzero4(); s[0][1] = fzero4();
            s[1][0] = fzero4(); s[1][1] = fzero4();
            __builtin_amdgcn_s_setprio(1);
#pragma unroll
            for (int tt = 0; tt < 2; ++tt)
#pragma unroll
                for (int ks = 0; ks < 2; ++ks) {
                    half8 kf = *(const half8*)(lK + sw8((2 * t + tt) * 16 + l15, ks * 32 + quad * 8));
                    s[0][tt] = __builtin_amdgcn_mfma_f32_16x16x32_f16(kf, qf[0][ks], s[0][tt], 0, 0, 0);
                    s[1][tt] = __builtin_amdgcn_mfma_f32_16x16x32_f16(kf, qf[1][ks], s[1][tt], 0, 0, 0);
                }
            __builtin_amdgcn_s_setprio(0);
            half8 pf[2];
#pragma unroll
            for (int qt = 0; qt < 2; ++qt) {
                half2v p01 = expp2(s[qt][0][0], s[qt][0][1]);
                half2v p23 = expp2(s[qt][0][2], s[qt][0][3]);
                half2v p45 = expp2(s[qt][1][0], s[qt][1][1]);
                half2v p67 = expp2(s[qt][1][2], s[qt][1][3]);
                half4 lo = __builtin_shufflevector(p01, p23, 0, 1, 2, 3);
                half4 hi = __builtin_shufflevector(p45, p67, 0, 1, 2, 3);
                pf[qt] = __builtin_shufflevector(lo, hi, 0, 1, 2, 3, 4, 5, 6, 7);
            }
            __builtin_amdgcn_s_setprio(1);
            lsum[0] = __builtin_amdgcn_mfma_f32_16x16x32_f16(pf[0], ones, lsum[0], 0, 0, 0);
            lsum[1] = __builtin_amdgcn_mfma_f32_16x16x32_f16(pf[1], ones, lsum[1], 0, 0, 0);
#pragma unroll
            for (int dt = 0; dt < 4; ++dt) {
                // single aligned half8: V^T key-permuted so lane quad's 8 keys
                // are contiguous at position t*32 + quad*8
                half8 vf = *(const half8*)(lV + sw8(dt * 16 + l15, t * 32 + quad * 8));
                O[0][dt] = __builtin_amdgcn_mfma_f32_16x16x32_f16(pf[0], vf, O[0][dt], 0, 0, 0);
                O[1][dt] = __builtin_amdgcn_mfma_f32_16x16x32_f16(pf[1], vf, O[1][dt], 0, 0, 0);
            }
            __builtin_amdgcn_s_setprio(0);
        }
    };

    // iter 0: compute set0 (set1's 4 loads stay in flight)
    ACQ(4);
    computeg(lbuf[g], lbuf[2 + g]);
    REL();
    // iters 1..14: issue iter it+1's set (into the buffer freed by it-1's
    // REL), wait iter it's set (vmcnt(4): newer 4 in flight), compute.
    for (int it = 1; it <= 14; ++it) {
        const int ns = ((it + 1) & 1) * 4;
        const long kb = (long)(it + 1) * 128;
        gl2lds16(ksrc + kb * NQKV,        (char*)lbuf[ns + 0] + tid * 16);
        gl2lds16(ksrc + (kb + 64) * NQKV, (char*)lbuf[ns + 1] + tid * 16);
        gl2lds16(vsrc + kb,               (char*)lbuf[ns + 2] + tid * 16);
        gl2lds16(vsrc + kb + 64,          (char*)lbuf[ns + 3] + tid * 16);
        const int cs = (it & 1) * 4;
        ACQ(4);
        computeg(lbuf[cs + g], lbuf[cs + 2 + g]);
        REL();
    }
    // iter 15: last set, nothing else in flight
    ACQ(0);
    computeg(lbuf[4 + g], lbuf[6 + g]);
    __syncthreads();   // drains ds reads; all 64 KB LDS now free for combine

    // wave-pair combine: waves 4-7 hand their partial O/lsum to waves 0-3.
    // stride 41 f32 per lane -> 41 mod 32 coprime -> conflict-free one-shot.
    float* red = (float*)lbuf;
    const int slot = (wq * 64 + lane) * 41;
    if (wave >= 4) {
        float* p = red + slot;
#pragma unroll
        for (int qt = 0; qt < 2; ++qt)
#pragma unroll
            for (int dt = 0; dt < 4; ++dt)
#pragma unroll
                for (int r = 0; r < 4; ++r) p[qt * 16 + dt * 4 + r] = O[qt][dt][r];
#pragma unroll
        for (int qt = 0; qt < 2; ++qt)
#pragma unroll
            for (int r = 0; r < 4; ++r) p[32 + qt * 4 + r] = lsum[qt][r];
    }
    __syncthreads();
    if (wave < 4) {
        const float* p = red + slot;
#pragma unroll
        for (int qt = 0; qt < 2; ++qt)
#pragma unroll
            for (int dt = 0; dt < 4; ++dt)
#pragma unroll
                for (int r = 0; r < 4; ++r) O[qt][dt][r] += p[qt * 16 + dt * 4 + r];
#pragma unroll
        for (int qt = 0; qt < 2; ++qt)
#pragma unroll
            for (int r = 0; r < 4; ++r) lsum[qt][r] += p[32 + qt * 4 + r];

        // epilogue: O / l (lsum in C-layout rows), store f16
#pragma unroll
        for (int qt = 0; qt < 2; ++qt) {
#pragma unroll
            for (int r = 0; r < 4; ++r) {
                const float lr = 1.0f / lsum[qt][r];
                const int row = b * SEQ + q0 + wq * 32 + qt * 16 + quad * 4 + r;
#pragma unroll
                for (int dt = 0; dt < 4; ++dt)
                    aout[(long)row * DM + h * HD + dt * 16 + l15] =
                        (_Float16)(O[qt][dt][r] * lr);
            }
        }
    }
}

// --------------------------------------------------------------------- launch
extern "C" void kernel_launch(void* const* d_in, const int* in_sizes, int n_in,
                              void* d_out, int out_size, void* d_ws, size_t ws_size,
                              hipStream_t stream) {
    const float* X    = (const float*)d_in[0];
    const float* Wqkv = (const float*)d_in[1];
    const float* bqkv = (const float*)d_in[2];
    const float* Wo   = (const float*)d_in[3];
    const float* bo   = (const float*)d_in[4];

    // workspace layout (56 MB total); Xh/Wqh/Woh contiguous for fused convert.
    // bscaled lives at the head of the atth region: consumed by the QKV GEMM
    // before attn overwrites atth.
    char* ws = (char*)d_ws;
    _Float16* Xh   = (_Float16*)(ws);                        //  8 MB  [MTOT, DM]
    _Float16* Wqh  = (_Float16*)(ws + (size_t)8  * 1048576); //  6 MB  [NQKV, DM]
    _Float16* Woh  = (_Float16*)(ws + (size_t)14 * 1048576); //  2 MB  [DM, DM]
    _Float16* qkvh = (_Float16*)(ws + (size_t)16 * 1048576); // 24 MB  [MTOT, NQKV]
    _Float16* vth  = (_Float16*)(ws + (size_t)40 * 1048576); //  8 MB  [B, H, HD, SEQ]
    _Float16* atth = (_Float16*)(ws + (size_t)48 * 1048576); //  8 MB  [MTOT, DM]
    float* bscaled = (float*)(ws + (size_t)48 * 1048576);    // 12 KB (dead after QKV GEMM)

    const int ncvt = (MTOT * DM + NQKV * DM + DM * DM) / 4;
    cvt_all<<<(ncvt + 255) / 256, 256, 0, stream>>>(X, Wqkv, Wo, bqkv, bscaled, Xh);

    gemm_nt<true><<<dim3(NQKV / 128, MTOT / 128), 256, 0, stream>>>(
        Xh, Wqh, bscaled, qkvh, MTOT, NQKV, DM);

    repack_v<<<dim3(SEQ / 32, NH, BATCH), 256, 0, stream>>>(qkvh, vth);

    attn_flash<<<dim3(SEQ / 128, NH, BATCH), 512, 0, stream>>>(qkvh, vth, atth);

    gemm_nt_64<false><<<dim3(DM / 128, MTOT / 64), 256, 0, stream>>>(
        atth, Woh, bo, d_out, MTOT, DM, DM);
}

// Round 8
// 177.118 us; speedup vs baseline: 1.0564x; 1.0360x over previous
//
#include <hip/hip_runtime.h>

// Problem constants
#define DM    1024
#define NH    16
#define HD    64
#define SEQ   2048
#define BATCH 2
#define NQKV  3072          // 3*DM
#define MTOT  4096          // BATCH*SEQ

using half2v = __attribute__((ext_vector_type(2))) _Float16;
using half4  = __attribute__((ext_vector_type(4))) _Float16;
using half8  = __attribute__((ext_vector_type(8))) _Float16;
using f32x4  = __attribute__((ext_vector_type(4))) float;

typedef const __attribute__((address_space(1))) unsigned int* gp_t;
typedef __attribute__((address_space(3))) unsigned int* lp_t;

// async global->LDS, 16B per lane. LDS dest is wave-uniform base + lane*16
// (HW-pinned), so LDS swizzle is implemented by permuting the global SOURCE
// column per lane; readers apply the same XOR.
__device__ __forceinline__ void gl2lds16(const void* g, void* l) {
    __builtin_amdgcn_global_load_lds((gp_t)g, (lp_t)l, 16, 0, 0);
}

__device__ __forceinline__ f32x4 fzero4() {
    f32x4 v; v[0] = 0.f; v[1] = 0.f; v[2] = 0.f; v[3] = 0.f; return v;
}

// XOR-swizzled LDS indexing (units = halves, chunks = 16B = 8 halves).
__device__ __forceinline__ int sw8(int row, int col) {   // 64-half rows
    return (row << 6) | ((((col >> 3) ^ row) & 7) << 3) | (col & 7);
}

#define CSCALE 0.18033688011112042f   // (1/8) * log2(e) — folded into Q weights

// packed exp2 + f32->f16 convert (v_exp_f32 x2 + v_cvt_pkrtz_f16_f32)
__device__ __forceinline__ half2v expp2(float a, float b) {
    return __builtin_bit_cast(half2v, __builtin_amdgcn_cvt_pkrtz(
        __builtin_amdgcn_exp2f(a), __builtin_amdgcn_exp2f(b)));
}

// T4 counted-vmcnt acquire / release barriers (raw s_barrier — __syncthreads
// would drain vmcnt(0) and serialize the pipeline).  sched_barrier(0) pins
// code motion across the inline-asm waits (rule #18).  USED IN ATTN ONLY:
// R5 showed the same transform on the 4-wave GEMM costs occupancy and
// regresses; m97-structure GEMMs keep the plain __syncthreads loop.
#define ACQ(N) do {                                             \
    asm volatile("s_waitcnt vmcnt(" #N ")" ::: "memory");       \
    __builtin_amdgcn_sched_barrier(0);                          \
    __builtin_amdgcn_s_barrier();                               \
    __builtin_amdgcn_sched_barrier(0);                          \
} while (0)
#define REL() do {                                              \
    __builtin_amdgcn_sched_barrier(0);                          \
    asm volatile("s_waitcnt lgkmcnt(0)" ::: "memory");          \
    __builtin_amdgcn_s_barrier();                               \
    __builtin_amdgcn_sched_barrier(0);                          \
} while (0)

// ------------------------------------------- fused fp32 -> fp16 (X, Wqkv, Wo)
// Also: scales the Q-rows of Wqkv by CSCALE (so QK^T scores arrive in
// exp2-ready units) and emits a matching scaled f32 copy of bqkv.
__global__ __launch_bounds__(256) void cvt_all(const float* __restrict__ X,
                                               const float* __restrict__ W1,
                                               const float* __restrict__ W2,
                                               const float* __restrict__ bqkv,
                                               float* __restrict__ bscaled,
                                               _Float16* __restrict__ out) {
    const int nX = MTOT * DM / 4, nW1 = NQKV * DM / 4, nW2 = DM * DM / 4;
    int i = blockIdx.x * 256 + threadIdx.x;
    if (i < NQKV) {
        const float b = bqkv[i];
        bscaled[i] = ((i % 192) < 64) ? b * CSCALE : b;
    }
    if (i >= nX + nW1 + nW2) return;
    float4 f;
    float sc = 1.0f;
    if (i < nX) {
        f = reinterpret_cast<const float4*>(X)[i];
    } else if (i < nX + nW1) {
        const int off = i - nX;
        f = reinterpret_cast<const float4*>(W1)[off];
        const int row = off >> 8;            // 256 float4 per 1024-wide row
        if ((row % 192) < 64) sc = CSCALE;   // Q-rows of Wqkv
    } else {
        f = reinterpret_cast<const float4*>(W2)[i - nX - nW1];
    }
    half4 h;
    h[0] = (_Float16)(f.x * sc); h[1] = (_Float16)(f.y * sc);
    h[2] = (_Float16)(f.z * sc); h[3] = (_Float16)(f.w * sc);
    reinterpret_cast<half4*>(out)[i] = h;
}

// ------------------------------------------------- NT GEMM (m97 structure)
// C[m][n] = sum_k A[m][k]*B[n][k] + bias[n].  128x128 tile, BK=64, 4 waves
// in 2x2, each wave 64x64 via 4x4 MFMA 16x16x32_f16 tiles. XOR-swizzled LDS.
// 32 KB LDS keeps 5 blocks/CU (R5 showed the counted-vmcnt dbuf at 64 KB
// drops occupancy and regresses 35->50.7 us).
//
// R8: EMIT_V fuses the old repack_v kernel into the epilogue.  For V columns
// (n%192 >= 128) the thread's 4 r-values map to 4 CONSECUTIVE permuted
// token-positions: token m = ..+quad*4+r -> si=quad, hi=bit4(m), rr=r ->
// position s0 + 8*quad + 4*hi + r.  One aligned 8B half4 store per (mt,nt).
// Saves a full kernel launch + 24 MB strided re-read + 8 MB write.
template <bool OUT_F16, bool EMIT_V>
__global__ __launch_bounds__(256) void gemm_nt(const _Float16* __restrict__ A,
                                               const _Float16* __restrict__ B,
                                               const float* __restrict__ bias,
                                               void* __restrict__ Cout,
                                               _Float16* __restrict__ vt,
                                               int M, int N, int K) {
    __shared__ _Float16 lA[128 * 64];
    __shared__ _Float16 lB[128 * 64];
    const int tid = threadIdx.x;
    const int m0 = blockIdx.y * 128, n0 = blockIdx.x * 128;
    const int wave = tid >> 6, lane = tid & 63, quad = lane >> 4, l15 = lane & 15;
    const int wm = (wave & 1) * 64, wn = (wave >> 1) * 64;

    f32x4 acc[4][4];
#pragma unroll
    for (int i = 0; i < 4; ++i)
#pragma unroll
        for (int j = 0; j < 4; ++j) acc[i][j] = fzero4();

    const int cperm = (((tid & 7) ^ (tid >> 3)) & 7) * 8;
    const _Float16* Ab = A + (long)(m0 + (tid >> 3)) * K + cperm;
    const _Float16* Bb = B + (long)(n0 + (tid >> 3)) * K + cperm;
    char* lAp = (char*)lA + tid * 16;
    char* lBp = (char*)lB + tid * 16;

    for (int kt = 0; kt < K; kt += 64) {
        __syncthreads();
#pragma unroll
        for (int j = 0; j < 4; ++j) {
            gl2lds16(Ab + (long)j * 32 * K + kt, lAp + j * 4096);
            gl2lds16(Bb + (long)j * 32 * K + kt, lBp + j * 4096);
        }
        __syncthreads();
#pragma unroll
        for (int ks = 0; ks < 2; ++ks) {
            half8 af[4], bfr[4];
#pragma unroll
            for (int t = 0; t < 4; ++t) {
                af[t]  = *(const half8*)(lA + sw8(wm + t * 16 + l15, ks * 32 + quad * 8));
                bfr[t] = *(const half8*)(lB + sw8(wn + t * 16 + l15, ks * 32 + quad * 8));
            }
#pragma unroll
            for (int mt = 0; mt < 4; ++mt)
#pragma unroll
                for (int nt = 0; nt < 4; ++nt)
                    acc[mt][nt] = __builtin_amdgcn_mfma_f32_16x16x32_f16(
                        af[mt], bfr[nt], acc[mt][nt], 0, 0, 0);
        }
    }

    float bs[4];
#pragma unroll
    for (int nt = 0; nt < 4; ++nt) bs[nt] = bias[n0 + wn + nt * 16 + l15];

#pragma unroll
    for (int mt = 0; mt < 4; ++mt) {
        const int mbase = m0 + wm + mt * 16 + quad * 4;   // token of r=0
#pragma unroll
        for (int nt = 0; nt < 4; ++nt) {
            const int n = n0 + wn + nt * 16 + l15;
            half4 hv;
#pragma unroll
            for (int r = 0; r < 4; ++r) {
                const float v = acc[mt][nt][r] + bs[nt];
                hv[r] = (_Float16)v;
                if constexpr (OUT_F16)
                    ((_Float16*)Cout)[(long)(mbase + r) * N + n] = (_Float16)v;
                else
                    ((float*)Cout)[(long)(mbase + r) * N + n] = v;
            }
            if constexpr (EMIT_V) {
                const int h = n / 192, w = n - h * 192;
                if (w >= 128) {
                    const int d  = w - 128;
                    const int bb = mbase >> 11, sq = mbase & (SEQ - 1);
                    const int s0v = sq & ~31, hi = (sq >> 4) & 1;
                    _Float16* dst = vt + ((long)(bb * NH + h) * HD + d) * SEQ
                                    + s0v + 8 * quad + 4 * hi;
                    *(half4*)dst = hv;
                }
            }
        }
    }
}

// -------------------------------- NT GEMM, 64x128 tile (more blocks for small N)
template <bool OUT_F16>
__global__ __launch_bounds__(256) void gemm_nt_64(const _Float16* __restrict__ A,
                                                  const _Float16* __restrict__ B,
                                                  const float* __restrict__ bias,
                                                  void* __restrict__ Cout,
                                                  int M, int N, int K) {
    __shared__ _Float16 lA[64 * 64];
    __shared__ _Float16 lB[128 * 64];
    const int tid = threadIdx.x;
    const int m0 = blockIdx.y * 64, n0 = blockIdx.x * 128;
    const int wave = tid >> 6, lane = tid & 63, quad = lane >> 4, l15 = lane & 15;
    const int wm = (wave & 1) * 32, wn = (wave >> 1) * 64;

    f32x4 acc[2][4];
#pragma unroll
    for (int i = 0; i < 2; ++i)
#pragma unroll
        for (int j = 0; j < 4; ++j) acc[i][j] = fzero4();

    const int cperm = (((tid & 7) ^ (tid >> 3)) & 7) * 8;
    const _Float16* Ab = A + (long)(m0 + (tid >> 3)) * K + cperm;
    const _Float16* Bb = B + (long)(n0 + (tid >> 3)) * K + cperm;
    char* lAp = (char*)lA + tid * 16;
    char* lBp = (char*)lB + tid * 16;

    for (int kt = 0; kt < K; kt += 64) {
        __syncthreads();
#pragma unroll
        for (int j = 0; j < 2; ++j)
            gl2lds16(Ab + (long)j * 32 * K + kt, lAp + j * 4096);
#pragma unroll
        for (int j = 0; j < 4; ++j)
            gl2lds16(Bb + (long)j * 32 * K + kt, lBp + j * 4096);
        __syncthreads();
#pragma unroll
        for (int ks = 0; ks < 2; ++ks) {
            half8 af[2], bfr[4];
#pragma unroll
            for (int t = 0; t < 2; ++t)
                af[t] = *(const half8*)(lA + sw8(wm + t * 16 + l15, ks * 32 + quad * 8));
#pragma unroll
            for (int t = 0; t < 4; ++t)
                bfr[t] = *(const half8*)(lB + sw8(wn + t * 16 + l15, ks * 32 + quad * 8));
#pragma unroll
            for (int mt = 0; mt < 2; ++mt)
#pragma unroll
                for (int nt = 0; nt < 4; ++nt)
                    acc[mt][nt] = __builtin_amdgcn_mfma_f32_16x16x32_f16(
                        af[mt], bfr[nt], acc[mt][nt], 0, 0, 0);
        }
    }

    float bs[4];
#pragma unroll
    for (int nt = 0; nt < 4; ++nt) bs[nt] = bias[n0 + wn + nt * 16 + l15];

#pragma unroll
    for (int mt = 0; mt < 2; ++mt) {
#pragma unroll
        for (int r = 0; r < 4; ++r) {
            const int m = m0 + wm + mt * 16 + quad * 4 + r;
#pragma unroll
            for (int nt = 0; nt < 4; ++nt) {
                const int n = n0 + wn + nt * 16 + l15;
                const float v = acc[mt][nt][r] + bs[nt];
                if constexpr (OUT_F16)
                    ((_Float16*)Cout)[(long)m * N + n] = (_Float16)v;
                else
                    ((float*)Cout)[(long)m * N + n] = v;
            }
        }
    }
}

// ----------------------------------------------------- flash attention fwd
// Per block: (b, h, 128 q-rows), 512 threads = 8 waves.  Waves are paired:
// wave w and w+4 both own q rows [(w&3)*32, +32) — group g=wave>>2 takes the
// even (g=0) / odd (g=1) 64-key tiles.  Each block-iter stages 128 keys
// (4 x 8KB tiles, ONE gl2lds16 each at 512 thr), double-buffered (64 KB).
// At the end wave pairs merge partial O/lsum through LDS (exp2-prescaled
// scores -> no max bookkeeping, partials just add).
//
// R8: setprio REMOVED (R7-vs-R4 A/B: +4 us / neutral — our lockstep
// barrier-synced waves have no role diversity, matching m190's null; the
// R5 "-8 us" inference was confounded by gemm_nt_64's pipelining).
// Technique stack: counted-vmcnt pipeline (R2) + 32q/wave operand reuse at
// 4 waves/SIMD via wave-pair key split (R4).
__global__ __launch_bounds__(512) void attn_flash(const _Float16* __restrict__ qkv,
                                                  const _Float16* __restrict__ vt,
                                                  _Float16* __restrict__ aout) {
    __shared__ _Float16 lbuf[8][64 * 64];   // 64 KB: 2 sets x {K0,K1,V0,V1}

    // XCD-aware decode (dispatch round-robins linear block id over 8 XCDs):
    // all 16 q-tiles of one (b,h) land on one XCD -> K/V re-reads hit its L2.
    const int L = blockIdx.x + 16 * blockIdx.y + 256 * blockIdx.z;  // 0..511
    const int c = L & 7, j = L >> 3;        // XCD c, 64 blocks per XCD
    const int pair = c * 4 + (j >> 4);      // 32 (b,h) pairs, 4 per XCD
    const int b = pair >> 4, h = pair & 15;
    const int q0 = (j & 15) * 128;

    const int tid = threadIdx.x;
    const int wave = tid >> 6, lane = tid & 63, quad = lane >> 4, l15 = lane & 15;
    const int wq = wave & 3;                // q-subtile (shared by wave pair)
    const int g  = wave >> 2;               // key-half group: 0=even, 1=odd tile
    const int cperm8 = (((tid & 7) ^ (tid >> 3)) & 7) * 8;
    const int srow = tid >> 3;              // 0..63: row staged by this thread

    // stage Q tile [128][64] (swizzled) into lbuf[0..1] (16 KB)
    const _Float16* qsrc = qkv + (long)(b * SEQ + q0 + srow) * NQKV + h * 192 + cperm8;
    gl2lds16(qsrc,                   (char*)lbuf + tid * 16);
    gl2lds16(qsrc + (long)64 * NQKV, (char*)lbuf + 8192 + tid * 16);
    __syncthreads();   // Q landed (drains vmcnt — prologue only)

    half8 qf[2][2];
#pragma unroll
    for (int qt = 0; qt < 2; ++qt)
#pragma unroll
        for (int ks = 0; ks < 2; ++ks)
            qf[qt][ks] = *(const half8*)((const _Float16*)lbuf +
                             sw8(wq * 32 + qt * 16 + l15, ks * 32 + quad * 8));
    __syncthreads();   // all Q reads done; K buffers free

    f32x4 O[2][4];
#pragma unroll
    for (int qt = 0; qt < 2; ++qt)
#pragma unroll
        for (int dt = 0; dt < 4; ++dt) O[qt][dt] = fzero4();
    f32x4 lsum[2] = {fzero4(), fzero4()};

    half8 ones;
#pragma unroll
    for (int i = 0; i < 8; ++i) ones[i] = (_Float16)1.0f;

    const _Float16* ksrc = qkv + (long)(b * SEQ + srow) * NQKV + h * 192 + 64 + cperm8;
    const _Float16* vsrc = vt + (long)((b * NH + h) * HD + srow) * SEQ + cperm8;

    // prologue: issue sets for iters 0 and 1 (kb = 0, 128).  Each 8 KB tile
    // is ONE gl2lds16 at 512 threads.  Outstanding per wave = 8.
#pragma unroll
    for (int s = 0; s < 2; ++s) {
        const long kb = (long)s * 128;
        gl2lds16(ksrc + kb * NQKV,         (char*)lbuf[s * 4 + 0] + tid * 16);
        gl2lds16(ksrc + (kb + 64) * NQKV,  (char*)lbuf[s * 4 + 1] + tid * 16);
        gl2lds16(vsrc + kb,                (char*)lbuf[s * 4 + 2] + tid * 16);
        gl2lds16(vsrc + kb + 64,           (char*)lbuf[s * 4 + 3] + tid * 16);
    }

    // per-64-key-tile compute for this wave's 32 q (2 MFMA per LDS read)
    auto computeg = [&](const _Float16* lK, const _Float16* lV) {
#pragma unroll
        for (int t = 0; t < 2; ++t) {
            f32x4 s[2][2];
            s[0][0] = fzero4(); s[0][1] = fzero4();
            s[1][0] = fzero4(); s[1][1] = fzero4();
#pragma unroll
            for (int tt = 0; tt < 2; ++tt)
#pragma unroll
                for (int ks = 0; ks < 2; ++ks) {
                    half8 kf = *(const half8*)(lK + sw8((2 * t + tt) * 16 + l15, ks * 32 + quad * 8));
                    s[0][tt] = __builtin_amdgcn_mfma_f32_16x16x32_f16(kf, qf[0][ks], s[0][tt], 0, 0, 0);
                    s[1][tt] = __builtin_amdgcn_mfma_f32_16x16x32_f16(kf, qf[1][ks], s[1][tt], 0, 0, 0);
                }
            half8 pf[2];
#pragma unroll
            for (int qt = 0; qt < 2; ++qt) {
                half2v p01 = expp2(s[qt][0][0], s[qt][0][1]);
                half2v p23 = expp2(s[qt][0][2], s[qt][0][3]);
                half2v p45 = expp2(s[qt][1][0], s[qt][1][1]);
                half2v p67 = expp2(s[qt][1][2], s[qt][1][3]);
                half4 lo = __builtin_shufflevector(p01, p23, 0, 1, 2, 3);
                half4 hi = __builtin_shufflevector(p45, p67, 0, 1, 2, 3);
                pf[qt] = __builtin_shufflevector(lo, hi, 0, 1, 2, 3, 4, 5, 6, 7);
                lsum[qt] = __builtin_amdgcn_mfma_f32_16x16x32_f16(pf[qt], ones, lsum[qt], 0, 0, 0);
            }
#pragma unroll
            for (int dt = 0; dt < 4; ++dt) {
                // single aligned half8: V^T key-permuted so lane quad's 8 keys
                // are contiguous at position t*32 + quad*8
                half8 vf = *(const half8*)(lV + sw8(dt * 16 + l15, t * 32 + quad * 8));
                O[0][dt] = __builtin_amdgcn_mfma_f32_16x16x32_f16(pf[0], vf, O[0][dt], 0, 0, 0);
                O[1][dt] = __builtin_amdgcn_mfma_f32_16x16x32_f16(pf[1], vf, O[1][dt], 0, 0, 0);
            }
        }
    };

    // iter 0: compute set0 (set1's 4 loads stay in flight)
    ACQ(4);
    computeg(lbuf[g], lbuf[2 + g]);
    REL();
    // iters 1..14: issue iter it+1's set (into the buffer freed by it-1's
    // REL), wait iter it's set (vmcnt(4): newer 4 in flight), compute.
    for (int it = 1; it <= 14; ++it) {
        const int ns = ((it + 1) & 1) * 4;
        const long kb = (long)(it + 1) * 128;
        gl2lds16(ksrc + kb * NQKV,        (char*)lbuf[ns + 0] + tid * 16);
        gl2lds16(ksrc + (kb + 64) * NQKV, (char*)lbuf[ns + 1] + tid * 16);
        gl2lds16(vsrc + kb,               (char*)lbuf[ns + 2] + tid * 16);
        gl2lds16(vsrc + kb + 64,          (char*)lbuf[ns + 3] + tid * 16);
        const int cs = (it & 1) * 4;
        ACQ(4);
        computeg(lbuf[cs + g], lbuf[cs + 2 + g]);
        REL();
    }
    // iter 15: last set, nothing else in flight
    ACQ(0);
    computeg(lbuf[4 + g], lbuf[6 + g]);
    __syncthreads();   // drains ds reads; all 64 KB LDS now free for combine

    // wave-pair combine: waves 4-7 hand their partial O/lsum to waves 0-3.
    // stride 41 f32 per lane -> 41 mod 32 coprime -> conflict-free one-shot.
    float* red = (float*)lbuf;
    const int slot = (wq * 64 + lane) * 41;
    if (wave >= 4) {
        float* p = red + slot;
#pragma unroll
        for (int qt = 0; qt < 2; ++qt)
#pragma unroll
            for (int dt = 0; dt < 4; ++dt)
#pragma unroll
                for (int r = 0; r < 4; ++r) p[qt * 16 + dt * 4 + r] = O[qt][dt][r];
#pragma unroll
        for (int qt = 0; qt < 2; ++qt)
#pragma unroll
            for (int r = 0; r < 4; ++r) p[32 + qt * 4 + r] = lsum[qt][r];
    }
    __syncthreads();
    if (wave < 4) {
        const float* p = red + slot;
#pragma unroll
        for (int qt = 0; qt < 2; ++qt)
#pragma unroll
            for (int dt = 0; dt < 4; ++dt)
#pragma unroll
                for (int r = 0; r < 4; ++r) O[qt][dt][r] += p[qt * 16 + dt * 4 + r];
#pragma unroll
        for (int qt = 0; qt < 2; ++qt)
#pragma unroll
            for (int r = 0; r < 4; ++r) lsum[qt][r] += p[32 + qt * 4 + r];

        // epilogue: O / l (lsum in C-layout rows), store f16
#pragma unroll
        for (int qt = 0; qt < 2; ++qt) {
#pragma unroll
            for (int r = 0; r < 4; ++r) {
                const float lr = 1.0f / lsum[qt][r];
                const int row = b * SEQ + q0 + wq * 32 + qt * 16 + quad * 4 + r;
#pragma unroll
                for (int dt = 0; dt < 4; ++dt)
                    aout[(long)row * DM + h * HD + dt * 16 + l15] =
                        (_Float16)(O[qt][dt][r] * lr);
            }
        }
    }
}

// --------------------------------------------------------------------- launch
extern "C" void kernel_launch(void* const* d_in, const int* in_sizes, int n_in,
                              void* d_out, int out_size, void* d_ws, size_t ws_size,
                              hipStream_t stream) {
    const float* X    = (const float*)d_in[0];
    const float* Wqkv = (const float*)d_in[1];
    const float* bqkv = (const float*)d_in[2];
    const float* Wo   = (const float*)d_in[3];
    const float* bo   = (const float*)d_in[4];

    // workspace layout (56 MB total); Xh/Wqh/Woh contiguous for fused convert.
    // bscaled lives at the head of the atth region: consumed by the QKV GEMM
    // before attn overwrites atth.
    char* ws = (char*)d_ws;
    _Float16* Xh   = (_Float16*)(ws);                        //  8 MB  [MTOT, DM]
    _Float16* Wqh  = (_Float16*)(ws + (size_t)8  * 1048576); //  6 MB  [NQKV, DM]
    _Float16* Woh  = (_Float16*)(ws + (size_t)14 * 1048576); //  2 MB  [DM, DM]
    _Float16* qkvh = (_Float16*)(ws + (size_t)16 * 1048576); // 24 MB  [MTOT, NQKV]
    _Float16* vth  = (_Float16*)(ws + (size_t)40 * 1048576); //  8 MB  [B, H, HD, SEQ]
    _Float16* atth = (_Float16*)(ws + (size_t)48 * 1048576); //  8 MB  [MTOT, DM]
    float* bscaled = (float*)(ws + (size_t)48 * 1048576);    // 12 KB (dead after QKV GEMM)

    const int ncvt = (MTOT * DM + NQKV * DM + DM * DM) / 4;
    cvt_all<<<(ncvt + 255) / 256, 256, 0, stream>>>(X, Wqkv, Wo, bqkv, bscaled, Xh);

    // QKV GEMM with fused V-repack (writes qkvh AND vth)
    gemm_nt<true, true><<<dim3(NQKV / 128, MTOT / 128), 256, 0, stream>>>(
        Xh, Wqh, bscaled, qkvh, vth, MTOT, NQKV, DM);

    attn_flash<<<dim3(SEQ / 128, NH, BATCH), 512, 0, stream>>>(qkvh, vth, atth);

    gemm_nt_64<false><<<dim3(DM / 128, MTOT / 64), 256, 0, stream>>>(
        atth, Woh, bo, d_out, MTOT, DM, DM);
}